// Round 6
// baseline (226.703 us; speedup 1.0000x reference)
//
#include <hip/hip_runtime.h>
#include <hip/hip_bf16.h>
#include <math.h>

#define CDIM  50257
#define BDIM  2048
#define TK    100
#define INTER 256
#define CIN   200
#define NBINS 4096
#define CAP   2048
#define BNEPS 1e-5f
#define THR   2.60f      // static candidate threshold; rank-100 of N(0,1)^50257 ~ 2.88
#define OVF   80.0f      // |x| beyond this risks expf overflow -> fallback

typedef float f32x4 __attribute__((ext_vector_type(4)));

__device__ __forceinline__ unsigned int ordered_bits(float x) {
    unsigned int u = __float_as_uint(x);
    return (u & 0x80000000u) ? ~u : (u | 0x80000000u);
}
__device__ __forceinline__ float inv_ordered(unsigned int o) {
    unsigned int u = (o & 0x80000000u) ? (o & 0x7fffffffu) : ~o;
    return __uint_as_float(u);
}
__device__ __forceinline__ void online1(float x, float& m, float& s) {
    if (x > m) { s = s * __expf(m - x) + 1.f; m = x; }
    else       { s += __expf(x - m); }
}
__device__ __forceinline__ void online4(f32x4 v, float& m, float& s) {
    float m4 = fmaxf(fmaxf(v.x, v.y), fmaxf(v.z, v.w));
    if (m4 > m) { s *= __expf(m - m4); m = m4; }
    s += __expf(v.x - m) + __expf(v.y - m) + __expf(v.z - m) + __expf(v.w - m);
}

// ---------------- kernel 0: transpose conv1_w [256][200] -> w1t [200][256] ----------------
__global__ __launch_bounds__(256) void transpose_w1(const float* __restrict__ w1,
                                                    float* __restrict__ w1t) {
    int o = blockIdx.x * 256 + threadIdx.x;
    if (o < INTER * CIN) {
        int c = o & (INTER - 1);
        int k = o >> 8;
        w1t[o] = w1[c * CIN + k];
    }
}

// ---------------- kernel 1: fused fast path (stream-sequential: teacher, then student) ----------------
__global__ __launch_bounds__(256, 8) void row_fast(const float* __restrict__ tea,
                                                   const float* __restrict__ stu,
                                                   const float* __restrict__ w1t,
                                                   const float* __restrict__ bias1,
                                                   float* __restrict__ h,
                                                   int* __restrict__ status) {
    __shared__ __align__(16) float cand_x[CAP];
    __shared__ int   cand_i[CAP];
    __shared__ float comb[CIN];
    __shared__ int   sel_idx[TK];
    __shared__ float redA[4], redB[4], redC[4], redD[4];
    __shared__ unsigned int cand_cnt;

    const int tid = threadIdx.x;
    const int row = blockIdx.x;
    const float* trow = tea + (size_t)row * CDIM;
    const float* srow = stu + (size_t)row * CDIM;
    const int pre  = (4 - (row & 3)) & 3;
    const int nv   = (CDIM - pre) >> 2;        // # aligned f32x4
    const int nv2  = nv & ~1;                  // even count for 2-wide loop
    const int tail = pre + (nv2 << 2);         // scalar tail start
    const f32x4* tv4 = (const f32x4*)(trow + pre);
    const f32x4* sv4 = (const f32x4*)(srow + pre);

    if (tid == 0) cand_cnt = 0u;
    __syncthreads();

    float sT = 0.f, mT = -INFINITY, sS = 0.f, mS = -INFINITY;

    // ---- teacher stream: sum/max + candidate collect (nt, 32B/thread/iter) ----
    for (int k = 2 * tid; k < nv2; k += 512) {
        f32x4 a0 = __builtin_nontemporal_load(tv4 + k);
        f32x4 a1 = __builtin_nontemporal_load(tv4 + k + 1);
        float a0m = fmaxf(fmaxf(a0.x, a0.y), fmaxf(a0.z, a0.w));
        float a1m = fmaxf(fmaxf(a1.x, a1.y), fmaxf(a1.z, a1.w));
        mT = fmaxf(mT, fmaxf(a0m, a1m));
        sT += ((__expf(a0.x) + __expf(a0.y)) + (__expf(a0.z) + __expf(a0.w)))
            + ((__expf(a1.x) + __expf(a1.y)) + (__expf(a1.z) + __expf(a1.w)));
        if (a0m >= THR) {
            int base = pre + (k << 2);
            if (a0.x >= THR) { unsigned p = atomicAdd(&cand_cnt, 1u); if (p < CAP) { cand_x[p] = a0.x; cand_i[p] = base;     } }
            if (a0.y >= THR) { unsigned p = atomicAdd(&cand_cnt, 1u); if (p < CAP) { cand_x[p] = a0.y; cand_i[p] = base + 1; } }
            if (a0.z >= THR) { unsigned p = atomicAdd(&cand_cnt, 1u); if (p < CAP) { cand_x[p] = a0.z; cand_i[p] = base + 2; } }
            if (a0.w >= THR) { unsigned p = atomicAdd(&cand_cnt, 1u); if (p < CAP) { cand_x[p] = a0.w; cand_i[p] = base + 3; } }
        }
        if (a1m >= THR) {
            int base = pre + ((k + 1) << 2);
            if (a1.x >= THR) { unsigned p = atomicAdd(&cand_cnt, 1u); if (p < CAP) { cand_x[p] = a1.x; cand_i[p] = base;     } }
            if (a1.y >= THR) { unsigned p = atomicAdd(&cand_cnt, 1u); if (p < CAP) { cand_x[p] = a1.y; cand_i[p] = base + 1; } }
            if (a1.z >= THR) { unsigned p = atomicAdd(&cand_cnt, 1u); if (p < CAP) { cand_x[p] = a1.z; cand_i[p] = base + 2; } }
            if (a1.w >= THR) { unsigned p = atomicAdd(&cand_cnt, 1u); if (p < CAP) { cand_x[p] = a1.w; cand_i[p] = base + 3; } }
        }
    }
    for (int i = tid; i < pre; i += 256) {
        float x = trow[i];
        mT = fmaxf(mT, x); sT += __expf(x);
        if (x >= THR) { unsigned p = atomicAdd(&cand_cnt, 1u); if (p < CAP) { cand_x[p] = x; cand_i[p] = i; } }
    }
    for (int i = tail + tid; i < CDIM; i += 256) {
        float x = trow[i];
        mT = fmaxf(mT, x); sT += __expf(x);
        if (x >= THR) { unsigned p = atomicAdd(&cand_cnt, 1u); if (p < CAP) { cand_x[p] = x; cand_i[p] = i; } }
    }

    // ---- student stream: sum/max only (nt, 32B/thread/iter) ----
    for (int k = 2 * tid; k < nv2; k += 512) {
        f32x4 b0 = __builtin_nontemporal_load(sv4 + k);
        f32x4 b1 = __builtin_nontemporal_load(sv4 + k + 1);
        float b0m = fmaxf(fmaxf(b0.x, b0.y), fmaxf(b0.z, b0.w));
        float b1m = fmaxf(fmaxf(b1.x, b1.y), fmaxf(b1.z, b1.w));
        mS = fmaxf(mS, fmaxf(b0m, b1m));
        sS += ((__expf(b0.x) + __expf(b0.y)) + (__expf(b0.z) + __expf(b0.w)))
            + ((__expf(b1.x) + __expf(b1.y)) + (__expf(b1.z) + __expf(b1.w)));
    }
    for (int i = tid; i < pre; i += 256)         { float y = srow[i]; mS = fmaxf(mS, y); sS += __expf(y); }
    for (int i = tail + tid; i < CDIM; i += 256) { float y = srow[i]; mS = fmaxf(mS, y); sS += __expf(y); }

#pragma unroll
    for (int o = 32; o; o >>= 1) {
        sT += __shfl_xor(sT, o, 64);
        sS += __shfl_xor(sS, o, 64);
        mT = fmaxf(mT, __shfl_xor(mT, o, 64));
        mS = fmaxf(mS, __shfl_xor(mS, o, 64));
    }
    if ((tid & 63) == 0) { int w = tid >> 6; redA[w] = sT; redB[w] = sS; redC[w] = mT; redD[w] = mS; }
    __syncthreads();
    const float ST = (redA[0] + redA[1]) + (redA[2] + redA[3]);
    const float SS = (redB[0] + redB[1]) + (redB[2] + redB[3]);
    const float MT = fmaxf(fmaxf(redC[0], redC[1]), fmaxf(redC[2], redC[3]));
    const float MS = fmaxf(fmaxf(redD[0], redD[1]), fmaxf(redD[2], redD[3]));

    const unsigned int cc = cand_cnt;
    const bool bad = (cc < TK) || (cc > CAP) || (MT > OVF) || (MS > OVF);
    if (tid == 0) status[row] = bad ? 1 : 0;
    if (bad) return;          // block-uniform; fixup kernel redoes this row exactly
    const int n = (int)cc;

    // candidates -> softmax probabilities (no max shift: e^x/S == e^(x-M)/S')
    for (int i = tid; i < n; i += 256) cand_x[i] = __expf(cand_x[i]) / ST;
    __syncthreads();

    // exact rank: descending p, ties -> lower index first
    for (int i = tid; i < n; i += 256) {
        float pi = cand_x[i];
        int   ii = cand_i[i];
        int r = 0;
        for (int j = 0; j < n; ++j) {
            float pj = cand_x[j];
            r += (pj > pi) || ((pj == pi) && (cand_i[j] < ii));
        }
        if (r < TK) { comb[r] = pi; sel_idx[r] = ii; }
    }
    __syncthreads();
    if (tid < TK) comb[TK + tid] = __expf(srow[sel_idx[tid]]) / SS;
    __syncthreads();

    float hc = bias1[tid];
#pragma unroll 4
    for (int k2 = 0; k2 < CIN; ++k2) hc = fmaf(comb[k2], w1t[k2 * INTER + tid], hc);
    h[(size_t)row * INTER + tid] = hc;
}

// ---------------- kernel 2: exact fixup (histogram algorithm), early-exits when clean ----------------
__global__ __launch_bounds__(256, 8) void row_fixup(const float* __restrict__ tea,
                                                    const float* __restrict__ stu,
                                                    const float* __restrict__ w1t,
                                                    const float* __restrict__ bias1,
                                                    float* __restrict__ h,
                                                    const int* __restrict__ status) {
    const int row = blockIdx.x;
    if (status[row] == 0) return;   // uniform: all threads exit before any barrier

    __shared__ __align__(16) unsigned char pool[NBINS * 4];
    unsigned int* hist   = (unsigned int*)pool;
    float*        cand_x = (float*)pool;
    int*          cand_i = (int*)(pool + CAP * sizeof(float));
    __shared__ unsigned int chunk[256];
    __shared__ float comb[CIN];
    __shared__ int   sel_idx[TK];
    __shared__ float red_a[4], red_b[4];
    __shared__ int   s_bin1;
    __shared__ unsigned int cand_cnt;

    const int tid = threadIdx.x;
    const float* trow = tea + (size_t)row * CDIM;
    const float* srow = stu + (size_t)row * CDIM;
    const int pre  = (4 - (row & 3)) & 3;
    const int nv   = (CDIM - pre) >> 2;
    const int tail = pre + (nv << 2);
    const f32x4* tv4 = (const f32x4*)(trow + pre);
    const f32x4* sv4 = (const f32x4*)(srow + pre);

    for (int i = tid; i < NBINS; i += 256) hist[i] = 0u;
    if (tid == 0) cand_cnt = 0u;
    __syncthreads();

    float m = -INFINITY, s = 0.f;
    for (int i = tid; i < pre; i += 256) {
        float x = trow[i];
        atomicAdd(&hist[ordered_bits(x) >> 20], 1u);
        online1(x, m, s);
    }
    for (int i = tail + tid; i < CDIM; i += 256) {
        float x = trow[i];
        atomicAdd(&hist[ordered_bits(x) >> 20], 1u);
        online1(x, m, s);
    }
    for (int k = tid; k < nv; k += 256) {
        f32x4 v = tv4[k];
        atomicAdd(&hist[ordered_bits(v.x) >> 20], 1u);
        atomicAdd(&hist[ordered_bits(v.y) >> 20], 1u);
        atomicAdd(&hist[ordered_bits(v.z) >> 20], 1u);
        atomicAdd(&hist[ordered_bits(v.w) >> 20], 1u);
        online4(v, m, s);
    }
#pragma unroll
    for (int o = 32; o; o >>= 1) {
        float mo = __shfl_xor(m, o, 64), so = __shfl_xor(s, o, 64);
        float mn = fmaxf(m, mo);
        s = s * __expf(m - mn) + so * __expf(mo - mn);
        m = mn;
    }
    if ((tid & 63) == 0) { red_a[tid >> 6] = m; red_b[tid >> 6] = s; }
    __syncthreads();
    float M = red_a[0], S = red_b[0];
#pragma unroll
    for (int w = 1; w < 4; ++w) {
        float mn = fmaxf(M, red_a[w]);
        S = S * __expf(M - mn) + red_b[w] * __expf(red_a[w] - mn);
        M = mn;
    }

    unsigned int cs = 0;
#pragma unroll
    for (int i = 0; i < NBINS / 256; ++i) cs += hist[tid * (NBINS / 256) + i];
    chunk[tid] = cs;
    __syncthreads();
    if (tid == 0) {
        unsigned int acc = 0;
        int t = 255;
        for (; t > 0; --t) {
            if (acc + chunk[t] >= TK) break;
            acc += chunk[t];
        }
        int b = t * 16;
        for (int i = 15; i >= 0; --i) {
            unsigned int hv = hist[t * 16 + i];
            if (acc + hv >= TK) { b = t * 16 + i; break; }
            acc += hv;
        }
        s_bin1 = b;
    }
    __syncthreads();
    const float thr = inv_ordered(((unsigned int)s_bin1) << 20);

    for (int i = tid; i < pre; i += 256) {
        float x = trow[i];
        if (x >= thr) { unsigned p = atomicAdd(&cand_cnt, 1u); if (p < CAP) { cand_x[p] = x; cand_i[p] = i; } }
    }
    for (int i = tail + tid; i < CDIM; i += 256) {
        float x = trow[i];
        if (x >= thr) { unsigned p = atomicAdd(&cand_cnt, 1u); if (p < CAP) { cand_x[p] = x; cand_i[p] = i; } }
    }
    for (int k = tid; k < nv; k += 256) {
        f32x4 v = tv4[k];
        int base = pre + 4 * k;
        if (v.x >= thr) { unsigned p = atomicAdd(&cand_cnt, 1u); if (p < CAP) { cand_x[p] = v.x; cand_i[p] = base; } }
        if (v.y >= thr) { unsigned p = atomicAdd(&cand_cnt, 1u); if (p < CAP) { cand_x[p] = v.y; cand_i[p] = base + 1; } }
        if (v.z >= thr) { unsigned p = atomicAdd(&cand_cnt, 1u); if (p < CAP) { cand_x[p] = v.z; cand_i[p] = base + 2; } }
        if (v.w >= thr) { unsigned p = atomicAdd(&cand_cnt, 1u); if (p < CAP) { cand_x[p] = v.w; cand_i[p] = base + 3; } }
    }
    __syncthreads();
    int n = (int)cand_cnt; if (n > CAP) n = CAP;

    for (int i = tid; i < n; i += 256) cand_x[i] = __expf(cand_x[i] - M) / S;
    __syncthreads();

    for (int i = tid; i < n; i += 256) {
        float pi = cand_x[i];
        int   ii = cand_i[i];
        int r = 0;
        for (int j = 0; j < n; ++j) {
            float pj = cand_x[j];
            r += (pj > pi) || ((pj == pi) && (cand_i[j] < ii));
        }
        if (r < TK) { comb[r] = pi; sel_idx[r] = ii; }
    }

    float m2 = -INFINITY, s2 = 0.f;
    for (int i = tid; i < pre; i += 256)         online1(srow[i], m2, s2);
    for (int i = tail + tid; i < CDIM; i += 256) online1(srow[i], m2, s2);
    for (int k = tid; k < nv; k += 256)          online4(sv4[k], m2, s2);
#pragma unroll
    for (int o = 32; o; o >>= 1) {
        float mo = __shfl_xor(m2, o, 64), so = __shfl_xor(s2, o, 64);
        float mn = fmaxf(m2, mo);
        s2 = s2 * __expf(m2 - mn) + so * __expf(mo - mn);
        m2 = mn;
    }
    __syncthreads();
    if ((tid & 63) == 0) { red_a[tid >> 6] = m2; red_b[tid >> 6] = s2; }
    __syncthreads();
    float M2 = red_a[0], S2 = red_b[0];
#pragma unroll
    for (int w = 1; w < 4; ++w) {
        float mn = fmaxf(M2, red_a[w]);
        S2 = S2 * __expf(M2 - mn) + red_b[w] * __expf(red_a[w] - mn);
        M2 = mn;
    }

    if (tid < TK) {
        float xg = srow[sel_idx[tid]];
        comb[TK + tid] = __expf(xg - M2) / S2;
    }
    __syncthreads();

    float hc = bias1[tid];
#pragma unroll 4
    for (int k2 = 0; k2 < CIN; ++k2) hc = fmaf(comb[k2], w1t[k2 * INTER + tid], hc);
    h[(size_t)row * INTER + tid] = hc;
}

// ---------------- kernel 3: batch-norm statistics ----------------
__global__ __launch_bounds__(256) void bn_stats(const float* __restrict__ h,
                                                float* __restrict__ mv) {
    const int c = blockIdx.x, tid = threadIdx.x;
    __shared__ float red[4];
    float v[BDIM / 256];
    float s = 0.f;
#pragma unroll
    for (int r = 0; r < BDIM / 256; ++r) {
        v[r] = h[(size_t)(r * 256 + tid) * INTER + c];
        s += v[r];
    }
#pragma unroll
    for (int o = 32; o; o >>= 1) s += __shfl_xor(s, o, 64);
    if ((tid & 63) == 0) red[tid >> 6] = s;
    __syncthreads();
    const float mu = ((red[0] + red[1]) + (red[2] + red[3])) * (1.f / BDIM);
    __syncthreads();
    float q = 0.f;
#pragma unroll
    for (int r = 0; r < BDIM / 256; ++r) { float d = v[r] - mu; q = fmaf(d, d, q); }
#pragma unroll
    for (int o = 32; o; o >>= 1) q += __shfl_xor(q, o, 64);
    if ((tid & 63) == 0) red[tid >> 6] = q;
    __syncthreads();
    if (tid == 0) {
        mv[c]         = mu;
        mv[INTER + c] = ((red[0] + red[1]) + (red[2] + red[3])) * (1.f / BDIM);
    }
}

// ---------------- kernel 4: BN apply + ReLU + conv2 -> out[row] ----------------
__global__ __launch_bounds__(256) void bn_out(const float* __restrict__ h,
                                              const float* __restrict__ mv,
                                              const float* __restrict__ gamma,
                                              const float* __restrict__ beta,
                                              const float* __restrict__ w2,
                                              const float* __restrict__ b2,
                                              float* __restrict__ out) {
    const int r = blockIdx.x, c = threadIdx.x;
    __shared__ float red[4];
    const float mu  = mv[c];
    const float var = mv[INTER + c];
    const float rs  = 1.0f / sqrtf(var + BNEPS);
    float hv = h[(size_t)r * INTER + c];
    float hn = gamma[c] * (hv - mu) * rs + beta[c];
    hn = fmaxf(hn, 0.f);
    float term = hn * w2[c];
#pragma unroll
    for (int o = 32; o; o >>= 1) term += __shfl_xor(term, o, 64);
    if ((c & 63) == 0) red[c >> 6] = term;
    __syncthreads();
    if (c == 0) out[r] = ((red[0] + red[1]) + (red[2] + red[3])) + b2[0];
}

extern "C" void kernel_launch(void* const* d_in, const int* in_sizes, int n_in,
                              void* d_out, int out_size, void* d_ws, size_t ws_size,
                              hipStream_t stream) {
    const float* tea   = (const float*)d_in[0];
    const float* stu   = (const float*)d_in[1];
    // d_in[2] = lambda_, unused in forward (gradient reversal is identity)
    const float* w1    = (const float*)d_in[3];
    const float* bias1 = (const float*)d_in[4];
    const float* gamma = (const float*)d_in[5];
    const float* beta  = (const float*)d_in[6];
    const float* w2    = (const float*)d_in[7];
    const float* b2    = (const float*)d_in[8];
    float* out = (float*)d_out;

    char* ws = (char*)d_ws;
    size_t off = 0;
    float* h      = (float*)(ws + off); off += (size_t)BDIM * INTER * sizeof(float);
    float* w1t    = (float*)(ws + off); off += (size_t)CIN * INTER * sizeof(float);
    float* mv     = (float*)(ws + off); off += 2 * INTER * sizeof(float);
    int*   status = (int*)(ws + off);

    transpose_w1<<<(INTER * CIN + 255) / 256, 256, 0, stream>>>(w1, w1t);
    row_fast <<<BDIM, 256, 0, stream>>>(tea, stu, w1t, bias1, h, status);
    row_fixup<<<BDIM, 256, 0, stream>>>(tea, stu, w1t, bias1, h, status);
    bn_stats <<<INTER, 256, 0, stream>>>(h, mv);
    bn_out   <<<BDIM, 256, 0, stream>>>(h, mv, gamma, beta, w2, b2, out);
}

// Round 7
// 205.889 us; speedup vs baseline: 1.1011x; 1.1011x over previous
//
#include <hip/hip_runtime.h>
#include <hip/hip_bf16.h>
#include <math.h>

#define CDIM  50257
#define BDIM  2048
#define TK    100
#define INTER 256
#define CIN   200
#define NBINS 4096
#define CAP   2048
#define BNEPS 1e-5f
#define THR   2.60f      // static candidate threshold; rank-100 of N(0,1)^50257 ~ 2.88

typedef float f32x4 __attribute__((ext_vector_type(4)));

__device__ __forceinline__ unsigned int ordered_bits(float x) {
    unsigned int u = __float_as_uint(x);
    return (u & 0x80000000u) ? ~u : (u | 0x80000000u);
}
__device__ __forceinline__ float inv_ordered(unsigned int o) {
    unsigned int u = (o & 0x80000000u) ? (o & 0x7fffffffu) : ~o;
    return __uint_as_float(u);
}
__device__ __forceinline__ void online1(float x, float& m, float& s) {
    if (x > m) { s = s * __expf(m - x) + 1.f; m = x; }
    else       { s += __expf(x - m); }
}
__device__ __forceinline__ void online4(f32x4 v, float& m, float& s) {
    float m4 = fmaxf(fmaxf(v.x, v.y), fmaxf(v.z, v.w));
    if (m4 > m) { s *= __expf(m - m4); m = m4; }
    s += __expf(v.x - m) + __expf(v.y - m) + __expf(v.z - m) + __expf(v.w - m);
}

// ---------------- kernel 0: transpose conv1_w [256][200] -> w1t [200][256] ----------------
__global__ __launch_bounds__(256) void transpose_w1(const float* __restrict__ w1,
                                                    float* __restrict__ w1t) {
    int o = blockIdx.x * 256 + threadIdx.x;
    if (o < INTER * CIN) {
        int c = o & (INTER - 1);
        int k = o >> 8;
        w1t[o] = w1[c * CIN + k];
    }
}

// collect one f32x4 of teacher candidates
#define COLLECT4(v, baseidx)                                                                                   \
    if (fmaxf(fmaxf(v.x, v.y), fmaxf(v.z, v.w)) >= THR) {                                                      \
        int base = (baseidx);                                                                                  \
        if (v.x >= THR) { unsigned p = atomicAdd(&cand_cnt, 1u); if (p < CAP) { cand_x[p] = v.x; cand_i[p] = base;     } } \
        if (v.y >= THR) { unsigned p = atomicAdd(&cand_cnt, 1u); if (p < CAP) { cand_x[p] = v.y; cand_i[p] = base + 1; } } \
        if (v.z >= THR) { unsigned p = atomicAdd(&cand_cnt, 1u); if (p < CAP) { cand_x[p] = v.z; cand_i[p] = base + 2; } } \
        if (v.w >= THR) { unsigned p = atomicAdd(&cand_cnt, 1u); if (p < CAP) { cand_x[p] = v.w; cand_i[p] = base + 3; } } \
    }

// ---------------- kernel 1: fused fast path (interleaved streams, pinned 4-deep load batch) ----------------
__global__ __launch_bounds__(256, 8) void row_fast(const float* __restrict__ tea,
                                                   const float* __restrict__ stu,
                                                   const float* __restrict__ w1t,
                                                   const float* __restrict__ bias1,
                                                   float* __restrict__ h,
                                                   int* __restrict__ status) {
    __shared__ __align__(16) float cand_x[CAP];
    __shared__ int   cand_i[CAP];
    __shared__ float comb[CIN];
    __shared__ int   sel_idx[TK];
    __shared__ float redA[4], redB[4];
    __shared__ unsigned int cand_cnt;

    const int tid = threadIdx.x;
    const int row = blockIdx.x;
    const float* trow = tea + (size_t)row * CDIM;
    const float* srow = stu + (size_t)row * CDIM;
    const int pre  = (4 - (row & 3)) & 3;
    const int nv   = (CDIM - pre) >> 2;
    const int tail = pre + (nv << 2);
    const f32x4* tv4 = (const f32x4*)(trow + pre);
    const f32x4* sv4 = (const f32x4*)(srow + pre);

    if (tid == 0) cand_cnt = 0u;
    __syncthreads();

    float sT = 0.f, sS = 0.f;

    for (int i = tid; i < pre; i += 256) {
        float x = trow[i], y = srow[i];
        sT += __expf(x); sS += __expf(y);
        if (x >= THR) { unsigned p = atomicAdd(&cand_cnt, 1u); if (p < CAP) { cand_x[p] = x; cand_i[p] = i; } }
    }
    for (int i = tail + tid; i < CDIM; i += 256) {
        float x = trow[i], y = srow[i];
        sT += __expf(x); sS += __expf(y);
        if (x >= THR) { unsigned p = atomicAdd(&cand_cnt, 1u); if (p < CAP) { cand_x[p] = x; cand_i[p] = i; } }
    }

    // main loop: 4 nt loads (T,S)x2 issued back-to-back, pinned via asm so the
    // compiler cannot sink them — one batched vmcnt drain per 16 elements.
    int k = tid;
    for (; k + 256 < nv; k += 512) {
        f32x4 a0 = __builtin_nontemporal_load(tv4 + k);
        f32x4 b0 = __builtin_nontemporal_load(sv4 + k);
        f32x4 a1 = __builtin_nontemporal_load(tv4 + k + 256);
        f32x4 b1 = __builtin_nontemporal_load(sv4 + k + 256);
        asm volatile("" : "+v"(a0), "+v"(b0), "+v"(a1), "+v"(b1));

        sT += ((__expf(a0.x) + __expf(a0.y)) + (__expf(a0.z) + __expf(a0.w)))
            + ((__expf(a1.x) + __expf(a1.y)) + (__expf(a1.z) + __expf(a1.w)));
        sS += ((__expf(b0.x) + __expf(b0.y)) + (__expf(b0.z) + __expf(b0.w)))
            + ((__expf(b1.x) + __expf(b1.y)) + (__expf(b1.z) + __expf(b1.w)));
        COLLECT4(a0, pre + (k << 2));
        COLLECT4(a1, pre + ((k + 256) << 2));
    }
    for (; k < nv; k += 256) {
        f32x4 a = __builtin_nontemporal_load(tv4 + k);
        f32x4 b = __builtin_nontemporal_load(sv4 + k);
        sT += (__expf(a.x) + __expf(a.y)) + (__expf(a.z) + __expf(a.w));
        sS += (__expf(b.x) + __expf(b.y)) + (__expf(b.z) + __expf(b.w));
        COLLECT4(a, pre + (k << 2));
    }

#pragma unroll
    for (int o = 32; o; o >>= 1) {
        sT += __shfl_xor(sT, o, 64);
        sS += __shfl_xor(sS, o, 64);
    }
    if ((tid & 63) == 0) { int w = tid >> 6; redA[w] = sT; redB[w] = sS; }
    __syncthreads();
    const float ST = (redA[0] + redA[1]) + (redA[2] + redA[3]);
    const float SS = (redB[0] + redB[1]) + (redB[2] + redB[3]);

    const unsigned int cc = cand_cnt;
    // inf/NaN in either sum (exp overflow or bad input) -> exact fixup path.
    const bool bad = (cc < TK) || (cc > CAP) ||
                     !(ST < __builtin_inff()) || !(SS < __builtin_inff());
    if (tid == 0) status[row] = bad ? 1 : 0;
    if (bad) return;          // block-uniform; fixup kernel redoes this row exactly
    const int n = (int)cc;

    // candidates -> softmax probabilities (no max shift: e^x/S == e^(x-M)/S')
    for (int i = tid; i < n; i += 256) cand_x[i] = __expf(cand_x[i]) / ST;
    __syncthreads();

    // exact rank: descending p, ties -> lower index first
    for (int i = tid; i < n; i += 256) {
        float pi = cand_x[i];
        int   ii = cand_i[i];
        int r = 0;
        for (int j = 0; j < n; ++j) {
            float pj = cand_x[j];
            r += (pj > pi) || ((pj == pi) && (cand_i[j] < ii));
        }
        if (r < TK) { comb[r] = pi; sel_idx[r] = ii; }
    }
    __syncthreads();
    if (tid < TK) comb[TK + tid] = __expf(srow[sel_idx[tid]]) / SS;
    __syncthreads();

    float hc = bias1[tid];
#pragma unroll 4
    for (int k2 = 0; k2 < CIN; ++k2) hc = fmaf(comb[k2], w1t[k2 * INTER + tid], hc);
    h[(size_t)row * INTER + tid] = hc;
}

// ---------------- kernel 2: exact fixup (histogram algorithm), early-exits when clean ----------------
__global__ __launch_bounds__(256, 8) void row_fixup(const float* __restrict__ tea,
                                                    const float* __restrict__ stu,
                                                    const float* __restrict__ w1t,
                                                    const float* __restrict__ bias1,
                                                    float* __restrict__ h,
                                                    const int* __restrict__ status) {
    const int row = blockIdx.x;
    if (status[row] == 0) return;   // uniform: all threads exit before any barrier

    __shared__ __align__(16) unsigned char pool[NBINS * 4];
    unsigned int* hist   = (unsigned int*)pool;
    float*        cand_x = (float*)pool;
    int*          cand_i = (int*)(pool + CAP * sizeof(float));
    __shared__ unsigned int chunk[256];
    __shared__ float comb[CIN];
    __shared__ int   sel_idx[TK];
    __shared__ float red_a[4], red_b[4];
    __shared__ int   s_bin1;
    __shared__ unsigned int cand_cnt;

    const int tid = threadIdx.x;
    const float* trow = tea + (size_t)row * CDIM;
    const float* srow = stu + (size_t)row * CDIM;
    const int pre  = (4 - (row & 3)) & 3;
    const int nv   = (CDIM - pre) >> 2;
    const int tail = pre + (nv << 2);
    const f32x4* tv4 = (const f32x4*)(trow + pre);
    const f32x4* sv4 = (const f32x4*)(srow + pre);

    for (int i = tid; i < NBINS; i += 256) hist[i] = 0u;
    if (tid == 0) cand_cnt = 0u;
    __syncthreads();

    float m = -INFINITY, s = 0.f;
    for (int i = tid; i < pre; i += 256) {
        float x = trow[i];
        atomicAdd(&hist[ordered_bits(x) >> 20], 1u);
        online1(x, m, s);
    }
    for (int i = tail + tid; i < CDIM; i += 256) {
        float x = trow[i];
        atomicAdd(&hist[ordered_bits(x) >> 20], 1u);
        online1(x, m, s);
    }
    for (int k = tid; k < nv; k += 256) {
        f32x4 v = tv4[k];
        atomicAdd(&hist[ordered_bits(v.x) >> 20], 1u);
        atomicAdd(&hist[ordered_bits(v.y) >> 20], 1u);
        atomicAdd(&hist[ordered_bits(v.z) >> 20], 1u);
        atomicAdd(&hist[ordered_bits(v.w) >> 20], 1u);
        online4(v, m, s);
    }
#pragma unroll
    for (int o = 32; o; o >>= 1) {
        float mo = __shfl_xor(m, o, 64), so = __shfl_xor(s, o, 64);
        float mn = fmaxf(m, mo);
        s = s * __expf(m - mn) + so * __expf(mo - mn);
        m = mn;
    }
    if ((tid & 63) == 0) { red_a[tid >> 6] = m; red_b[tid >> 6] = s; }
    __syncthreads();
    float M = red_a[0], S = red_b[0];
#pragma unroll
    for (int w = 1; w < 4; ++w) {
        float mn = fmaxf(M, red_a[w]);
        S = S * __expf(M - mn) + red_b[w] * __expf(red_a[w] - mn);
        M = mn;
    }

    unsigned int cs = 0;
#pragma unroll
    for (int i = 0; i < NBINS / 256; ++i) cs += hist[tid * (NBINS / 256) + i];
    chunk[tid] = cs;
    __syncthreads();
    if (tid == 0) {
        unsigned int acc = 0;
        int t = 255;
        for (; t > 0; --t) {
            if (acc + chunk[t] >= TK) break;
            acc += chunk[t];
        }
        int b = t * 16;
        for (int i = 15; i >= 0; --i) {
            unsigned int hv = hist[t * 16 + i];
            if (acc + hv >= TK) { b = t * 16 + i; break; }
            acc += hv;
        }
        s_bin1 = b;
    }
    __syncthreads();
    const float thr = inv_ordered(((unsigned int)s_bin1) << 20);

    for (int i = tid; i < pre; i += 256) {
        float x = trow[i];
        if (x >= thr) { unsigned p = atomicAdd(&cand_cnt, 1u); if (p < CAP) { cand_x[p] = x; cand_i[p] = i; } }
    }
    for (int i = tail + tid; i < CDIM; i += 256) {
        float x = trow[i];
        if (x >= thr) { unsigned p = atomicAdd(&cand_cnt, 1u); if (p < CAP) { cand_x[p] = x; cand_i[p] = i; } }
    }
    for (int k = tid; k < nv; k += 256) {
        f32x4 v = tv4[k];
        int base = pre + 4 * k;
        if (v.x >= thr) { unsigned p = atomicAdd(&cand_cnt, 1u); if (p < CAP) { cand_x[p] = v.x; cand_i[p] = base; } }
        if (v.y >= thr) { unsigned p = atomicAdd(&cand_cnt, 1u); if (p < CAP) { cand_x[p] = v.y; cand_i[p] = base + 1; } }
        if (v.z >= thr) { unsigned p = atomicAdd(&cand_cnt, 1u); if (p < CAP) { cand_x[p] = v.z; cand_i[p] = base + 2; } }
        if (v.w >= thr) { unsigned p = atomicAdd(&cand_cnt, 1u); if (p < CAP) { cand_x[p] = v.w; cand_i[p] = base + 3; } }
    }
    __syncthreads();
    int n = (int)cand_cnt; if (n > CAP) n = CAP;

    for (int i = tid; i < n; i += 256) cand_x[i] = __expf(cand_x[i] - M) / S;
    __syncthreads();

    for (int i = tid; i < n; i += 256) {
        float pi = cand_x[i];
        int   ii = cand_i[i];
        int r = 0;
        for (int j = 0; j < n; ++j) {
            float pj = cand_x[j];
            r += (pj > pi) || ((pj == pi) && (cand_i[j] < ii));
        }
        if (r < TK) { comb[r] = pi; sel_idx[r] = ii; }
    }

    float m2 = -INFINITY, s2 = 0.f;
    for (int i = tid; i < pre; i += 256)         online1(srow[i], m2, s2);
    for (int i = tail + tid; i < CDIM; i += 256) online1(srow[i], m2, s2);
    for (int k = tid; k < nv; k += 256)          online4(sv4[k], m2, s2);
#pragma unroll
    for (int o = 32; o; o >>= 1) {
        float mo = __shfl_xor(m2, o, 64), so = __shfl_xor(s2, o, 64);
        float mn = fmaxf(m2, mo);
        s2 = s2 * __expf(m2 - mn) + so * __expf(mo - mn);
        m2 = mn;
    }
    __syncthreads();
    if ((tid & 63) == 0) { red_a[tid >> 6] = m2; red_b[tid >> 6] = s2; }
    __syncthreads();
    float M2 = red_a[0], S2 = red_b[0];
#pragma unroll
    for (int w = 1; w < 4; ++w) {
        float mn = fmaxf(M2, red_a[w]);
        S2 = S2 * __expf(M2 - mn) + red_b[w] * __expf(red_a[w] - mn);
        M2 = mn;
    }

    if (tid < TK) {
        float xg = srow[sel_idx[tid]];
        comb[TK + tid] = __expf(xg - M2) / S2;
    }
    __syncthreads();

    float hc = bias1[tid];
#pragma unroll 4
    for (int k2 = 0; k2 < CIN; ++k2) hc = fmaf(comb[k2], w1t[k2 * INTER + tid], hc);
    h[(size_t)row * INTER + tid] = hc;
}

// ---------------- kernel 3: batch-norm statistics ----------------
__global__ __launch_bounds__(256) void bn_stats(const float* __restrict__ h,
                                                float* __restrict__ mv) {
    const int c = blockIdx.x, tid = threadIdx.x;
    __shared__ float red[4];
    float v[BDIM / 256];
    float s = 0.f;
#pragma unroll
    for (int r = 0; r < BDIM / 256; ++r) {
        v[r] = h[(size_t)(r * 256 + tid) * INTER + c];
        s += v[r];
    }
#pragma unroll
    for (int o = 32; o; o >>= 1) s += __shfl_xor(s, o, 64);
    if ((tid & 63) == 0) red[tid >> 6] = s;
    __syncthreads();
    const float mu = ((red[0] + red[1]) + (red[2] + red[3])) * (1.f / BDIM);
    __syncthreads();
    float q = 0.f;
#pragma unroll
    for (int r = 0; r < BDIM / 256; ++r) { float d = v[r] - mu; q = fmaf(d, d, q); }
#pragma unroll
    for (int o = 32; o; o >>= 1) q += __shfl_xor(q, o, 64);
    if ((tid & 63) == 0) red[tid >> 6] = q;
    __syncthreads();
    if (tid == 0) {
        mv[c]         = mu;
        mv[INTER + c] = ((red[0] + red[1]) + (red[2] + red[3])) * (1.f / BDIM);
    }
}

// ---------------- kernel 4: BN apply + ReLU + conv2 -> out[row] ----------------
__global__ __launch_bounds__(256) void bn_out(const float* __restrict__ h,
                                              const float* __restrict__ mv,
                                              const float* __restrict__ gamma,
                                              const float* __restrict__ beta,
                                              const float* __restrict__ w2,
                                              const float* __restrict__ b2,
                                              float* __restrict__ out) {
    const int r = blockIdx.x, c = threadIdx.x;
    __shared__ float red[4];
    const float mu  = mv[c];
    const float var = mv[INTER + c];
    const float rs  = 1.0f / sqrtf(var + BNEPS);
    float hv = h[(size_t)r * INTER + c];
    float hn = gamma[c] * (hv - mu) * rs + beta[c];
    hn = fmaxf(hn, 0.f);
    float term = hn * w2[c];
#pragma unroll
    for (int o = 32; o; o >>= 1) term += __shfl_xor(term, o, 64);
    if ((c & 63) == 0) red[c >> 6] = term;
    __syncthreads();
    if (c == 0) out[r] = ((red[0] + red[1]) + (red[2] + red[3])) + b2[0];
}

extern "C" void kernel_launch(void* const* d_in, const int* in_sizes, int n_in,
                              void* d_out, int out_size, void* d_ws, size_t ws_size,
                              hipStream_t stream) {
    const float* tea   = (const float*)d_in[0];
    const float* stu   = (const float*)d_in[1];
    // d_in[2] = lambda_, unused in forward (gradient reversal is identity)
    const float* w1    = (const float*)d_in[3];
    const float* bias1 = (const float*)d_in[4];
    const float* gamma = (const float*)d_in[5];
    const float* beta  = (const float*)d_in[6];
    const float* w2    = (const float*)d_in[7];
    const float* b2    = (const float*)d_in[8];
    float* out = (float*)d_out;

    char* ws = (char*)d_ws;
    size_t off = 0;
    float* h      = (float*)(ws + off); off += (size_t)BDIM * INTER * sizeof(float);
    float* w1t    = (float*)(ws + off); off += (size_t)CIN * INTER * sizeof(float);
    float* mv     = (float*)(ws + off); off += 2 * INTER * sizeof(float);
    int*   status = (int*)(ws + off);

    transpose_w1<<<(INTER * CIN + 255) / 256, 256, 0, stream>>>(w1, w1t);
    row_fast <<<BDIM, 256, 0, stream>>>(tea, stu, w1t, bias1, h, status);
    row_fixup<<<BDIM, 256, 0, stream>>>(tea, stu, w1t, bias1, h, status);
    bn_stats <<<INTER, 256, 0, stream>>>(h, mv);
    bn_out   <<<BDIM, 256, 0, stream>>>(h, mv, gamma, beta, w2, b2, out);
}